// Round 7
// baseline (111.848 us; speedup 1.0000x reference)
//
#include <hip/hip_runtime.h>
#include <hip/hip_bf16.h>

#define HH 12
#define DD 64
#define NB1 28
#define NB2 52
#define NF 2
#define FB1 56           // NF*NB1
#define FB2 104          // NF*NB2
#define STRIDE_HD 768    // HH*DD
#define SCALEF 0.125f

typedef float f32x4 __attribute__((ext_vector_type(4)));
typedef float f32x16 __attribute__((ext_vector_type(16)));
typedef short bf16x8 __attribute__((ext_vector_type(8)));

#if __has_builtin(__builtin_amdgcn_exp2f)
#define EXP2(x) __builtin_amdgcn_exp2f(x)
#else
#define EXP2(x) __expf((x) * 0.6931471805599453f)
#endif

__device__ __forceinline__ unsigned short f2bf(float x) {
  union { float f; unsigned u; } c; c.f = x;
  unsigned r = c.u + 0x7fffu + ((c.u >> 16) & 1u);
  return (unsigned short)(r >> 16);
}

// ===========================================================================
// k_proj: 64-row x 64-out projection tiles + rope, outputs key-grouped.
// ===========================================================================
__global__ __launch_bounds__(256, 4)
void k_proj(const float* __restrict__ lk, const float* __restrict__ rq,
            const float* __restrict__ cosb, const float* __restrict__ sinb,
            const float* __restrict__ W_lkk, const float* __restrict__ b_lkk,
            const float* __restrict__ W_rqk, const float* __restrict__ b_rqk,
            const float* __restrict__ W_lkq, const float* __restrict__ b_lkq,
            const float* __restrict__ W_rqq, const float* __restrict__ b_rqq,
            float* __restrict__ Klg, float* __restrict__ Krg,
            float* __restrict__ ql, float* __restrict__ qr) {
  __shared__ __align__(16) float Wt[64][68];   // [d][e]
  __shared__ __align__(16) float xs[64][68];   // [r][d]
  __shared__ int srows[64];
  __shared__ int obase[64];

  const int tid = threadIdx.x;
  int bx = blockIdx.x;
  int path, h, c;
  if (bx < 552)       { path = 0; h = bx / 46; c = bx % 46; }
  else if (bx < 1104) { path = 1; bx -= 552;  h = bx / 46; c = bx % 46; }
  else if (bx < 1116) { path = 2; h = bx - 1104; c = 0; }
  else                { path = 3; bx -= 1116; h = bx >> 1; c = bx & 1; }

  const float* X  = (path == 1 || path == 3) ? rq : lk;
  const float* W  = (path == 0) ? W_lkk : (path == 1) ? W_rqk : (path == 2) ? W_lkq : W_rqq;
  const float* bb = (path == 0) ? b_lkk : (path == 1) ? b_rqk : (path == 2) ? b_lkq : b_rqq;
  float* out      = (path == 0) ? Klg : (path == 1) ? Krg : (path == 2) ? ql : qr;
  const int nrows = (path == 0 || path == 1) ? ((c == 45) ? 32 : 64)
                   : (path == 2) ? 56 : ((c == 1) ? 40 : 64);

  for (int idx = tid; idx < 4096; idx += 256)
    Wt[idx & 63][idx >> 6] = W[(size_t)h * 4096 + idx];
  if (tid < 64) {
    int rr = tid, s = 0, ob = 0;
    if (rr < nrows) {
      if (path == 0) {
        s = c * 64 + rr;
        int f = s / 1456, rem = s % 1456, b1 = rem / 52, b2 = rem % 52;
        ob = ((h * 56 + f * 28 + b1) * 52 + b2) * 64;
      } else if (path == 1) {
        s = c * 64 + rr;
        int f = s / 1456, rem = s % 1456, b1 = rem / 52, jj = rem % 52;
        ob = ((h * 104 + f * 52 + jj) * 28 + b1) * 64;
      } else if (path == 2) {
        int q = rr;
        s = (q / 28) * 1456 + (q % 28) * 52;
        ob = (h * 56 + q) * 64;
      } else {
        int q = c * 64 + rr;
        s = (q / 52) * 1456 + (q % 52);
        ob = (h * 104 + q) * 64;
      }
    }
    srows[rr] = s; obase[rr] = ob;
  }
  __syncthreads();
  for (int idx = tid; idx < 4096; idx += 256) {
    int r = idx >> 6, d = idx & 63;
    xs[r][d] = X[(size_t)srows[r] * STRIDE_HD + h * DD + d];
  }
  __syncthreads();

  const int it = tid >> 4, kt = tid & 15;
  f32x4 acc0 = {0,0,0,0}, acc1 = {0,0,0,0}, acc2 = {0,0,0,0}, acc3 = {0,0,0,0};
  #pragma unroll 4
  for (int d4 = 0; d4 < 16; ++d4) {
    f32x4 x0 = *(const f32x4*)&xs[4 * it][4 * d4];
    f32x4 x1 = *(const f32x4*)&xs[4 * it + 1][4 * d4];
    f32x4 x2 = *(const f32x4*)&xs[4 * it + 2][4 * d4];
    f32x4 x3 = *(const f32x4*)&xs[4 * it + 3][4 * d4];
    #pragma unroll
    for (int dd = 0; dd < 4; ++dd) {
      f32x4 wv = *(const f32x4*)&Wt[4 * d4 + dd][4 * kt];
      acc0 += x0[dd] * wv;
      acc1 += x1[dd] * wv;
      acc2 += x2[dd] * wv;
      acc3 += x3[dd] * wv;
    }
  }

  f32x4 bv;
  bv[0] = bb[h * 64 + 4 * kt];     bv[1] = bb[h * 64 + 4 * kt + 1];
  bv[2] = bb[h * 64 + 4 * kt + 2]; bv[3] = bb[h * 64 + 4 * kt + 3];
  #pragma unroll
  for (int rr = 0; rr < 4; ++rr) {
    int row = 4 * it + rr;
    if (row < nrows) {
      f32x4 o = (rr == 0) ? acc0 : (rr == 1) ? acc1 : (rr == 2) ? acc2 : acc3;
      o += bv;
      int s = srows[row];
      float c0 = cosb[s * 32 + 2 * kt],     s0 = sinb[s * 32 + 2 * kt];
      float c1 = cosb[s * 32 + 2 * kt + 1], s1 = sinb[s * 32 + 2 * kt + 1];
      f32x4 res;
      res[0] = o[0] * c0 - o[1] * s0;
      res[1] = o[1] * c0 + o[0] * s0;
      res[2] = o[2] * c1 - o[3] * s1;
      res[3] = o[3] * c1 + o[2] * s1;
      *(f32x4*)(out + obase[row] + 4 * kt) = res;
    }
  }
}

// ===========================================================================
// k_sv: per-(n,h) tiny SDPA (wide phases) for both paths + V bf16 re-layout
// ===========================================================================
struct SvShared {
  union {
    struct { float qv[64]; float sc[64]; float ps[64]; float ys[64]; float oe[64]; } s;
    float tile[52][68];
  } u;
};

template<int NK, int NG, int GD, int GMUL, int KSTR>
__device__ void sdpa_path(int n, int h, const float* __restrict__ X,
                          const float* __restrict__ Kg, const float* __restrict__ qb,
                          const float* __restrict__ cosb, const float* __restrict__ sinb,
                          const float* __restrict__ Wv, const float* __restrict__ bvv,
                          float* __restrict__ outb, SvShared& sm) {
  const int t = threadIdx.x;
  const int f = n / GD, g = n % GD;
  const int s_base = f * (NB1 * NB2) + g * GMUL;

  if (t < 64) sm.u.s.qv[t] = qb[(size_t)(h * NG + n) * 64 + t];
  __syncthreads();

  if (t < NK * 4) {
    int r = t >> 2, part = t & 3;
    const float4* kr = (const float4*)(Kg + ((size_t)(h * NG + n) * NK + r) * 64 + part * 16);
    const float4* q4 = (const float4*)(sm.u.s.qv + part * 16);
    float p = 0.f;
    #pragma unroll
    for (int i = 0; i < 4; ++i) {
      float4 kv = kr[i], qv4 = q4[i];
      p += kv.x * qv4.x + kv.y * qv4.y + kv.z * qv4.z + kv.w * qv4.w;
    }
    p += __shfl_xor(p, 1); p += __shfl_xor(p, 2);
    if (part == 0) sm.u.s.sc[r] = p * SCALEF;
  }
  __syncthreads();

  if (t < 64) {
    float v = (t < NK) ? sm.u.s.sc[t] : -1e30f;
    float mx = v;
    for (int o = 32; o; o >>= 1) mx = fmaxf(mx, __shfl_xor(mx, o));
    float e = (t < NK) ? __expf(v - mx) : 0.f;
    float sum = e;
    for (int o = 32; o; o >>= 1) sum += __shfl_xor(sum, o);
    sm.u.s.ps[t] = (t < NK) ? e / sum : 0.f;
  }
  __syncthreads();

  {
    int d = t >> 2, g4 = t & 3;
    constexpr int RPG = NK / 4;
    float yp = 0.f;
    #pragma unroll 4
    for (int rr = 0; rr < RPG; ++rr) {
      int r = g4 * RPG + rr;
      yp += sm.u.s.ps[r] * X[(size_t)(s_base + r * KSTR) * STRIDE_HD + h * DD + d];
    }
    yp += __shfl_xor(yp, 1); yp += __shfl_xor(yp, 2);
    if (g4 == 0) sm.u.s.ys[d] = yp;
  }
  __syncthreads();

  {
    int e = t >> 2, part = t & 3;
    const float4* wr = (const float4*)(Wv + (size_t)h * 4096 + e * 64 + part * 16);
    const float4* y4 = (const float4*)(sm.u.s.ys + part * 16);
    float p = 0.f;
    #pragma unroll
    for (int i = 0; i < 4; ++i) {
      float4 wv = wr[i], yv = y4[i];
      p += wv.x * yv.x + wv.y * yv.y + wv.z * yv.z + wv.w * yv.w;
    }
    p += __shfl_xor(p, 1); p += __shfl_xor(p, 2);
    if (part == 0) sm.u.s.oe[e] = p + bvv[h * 64 + e];
  }
  __syncthreads();

  if (t < 32) {
    float co = cosb[s_base * 32 + t], si = sinb[s_base * 32 + t];
    float o0 = sm.u.s.oe[2 * t], o1 = sm.u.s.oe[2 * t + 1];
    outb[(size_t)n * STRIDE_HD + h * DD + 2 * t]     = o0 * co - o1 * si;
    outb[(size_t)n * STRIDE_HD + h * DD + 2 * t + 1] = o1 * co + o0 * si;
  }
}

// v (S,H,D) f32 -> vb2[h][fk][l8][d][li] bf16 (l = l8*8+li, l>=52 zero)
__device__ void vb_path(int fk, int h, const float* __restrict__ v,
                        unsigned short* __restrict__ vb2, SvShared& sm) {
  const int tid = threadIdx.x;
  for (int idx = tid; idx < NB2 * DD; idx += 256) {
    int l = idx >> 6, d = idx & 63;
    sm.u.tile[l][d] = v[(size_t)(fk * NB2 + l) * STRIDE_HD + h * DD + d];
  }
  __syncthreads();
  for (int idx = tid; idx < 512; idx += 256) {
    int l8 = idx >> 6, d = idx & 63;
    unsigned short tmp[8];
    #pragma unroll
    for (int li = 0; li < 8; ++li) {
      int l = l8 * 8 + li;
      tmp[li] = (l < NB2) ? f2bf(sm.u.tile[l][d]) : (unsigned short)0;
    }
    bf16x8* dst = (bf16x8*)(vb2 + (((size_t)(h * FB1 + fk) * 8 + l8) * 64 + d) * 8);
    *dst = *(bf16x8*)tmp;
  }
}

__global__ __launch_bounds__(256)
void k_sv(const float* __restrict__ lk, const float* __restrict__ rq,
          const float* __restrict__ v,
          const float* __restrict__ cosb, const float* __restrict__ sinb,
          const float* __restrict__ Klg, const float* __restrict__ Krg,
          const float* __restrict__ ql, const float* __restrict__ qr,
          const float* __restrict__ W_lkv, const float* __restrict__ b_lkv,
          const float* __restrict__ W_rqv, const float* __restrict__ b_rqv,
          float* __restrict__ lk_out, float* __restrict__ rq_out,
          unsigned short* __restrict__ vb2) {
  __shared__ SvShared sm;
  const int bx = blockIdx.x;
  if (bx < 672) {
    sdpa_path<52, 56, 28, 52, 1>(bx % 56, bx / 56, lk, Klg, ql, cosb, sinb,
                                 W_lkv, b_lkv, lk_out, sm);
  } else if (bx < 1920) {
    int id = bx - 672;
    sdpa_path<28, 104, 52, 1, 52>(id % 104, id / 104, rq, Krg, qr, cosb, sinb,
                                  W_rqv, b_rqv, rq_out, sm);
  } else {
    int id = bx - 1920;
    vb_path(id % 56, id / 56, v, vb2, sm);
  }
}

// ===========================================================================
// MID: L and R contractions, 4x4 register tiles, single compute round.
// L blocks: 1248 (h,a,j). R blocks: 1344 (h,fk,aa) — LDS 28.3KB -> 5 blk/CU.
// ===========================================================================
struct MidLShared { float qs[NB1][68]; float ks[FB1][68]; };
struct MidRShared { float ks[NB2][68]; float qs[NB2][68]; };
union MidShared { MidLShared L; MidRShared R; };

__device__ void L_path(int bid, const float* __restrict__ lq,
                       const float* __restrict__ cosb, const float* __restrict__ sinb,
                       const float* __restrict__ lk_out, float* __restrict__ Lbuf,
                       MidLShared& sh) {
  const int h = bid / (NF * NB2);
  const int rem = bid % (NF * NB2);
  const int a = rem / NB2, j = rem % NB2;
  const int tid = threadIdx.x;
  for (int idx = tid; idx < NB1 * 32; idx += 256) {
    int i = idx >> 5, mm = idx & 31;
    int srow = a * (NB1 * NB2) + i * NB2 + j;
    const float* xr = lq + (size_t)srow * STRIDE_HD + h * DD;
    float x0 = xr[2 * mm], x1 = xr[2 * mm + 1];
    float co = cosb[srow * 32 + mm], si = sinb[srow * 32 + mm];
    sh.qs[i][2 * mm]     = x0 * co - x1 * si;
    sh.qs[i][2 * mm + 1] = x1 * co + x0 * si;
  }
  for (int idx = tid; idx < FB1 * DD; idx += 256) {
    int r = idx >> 6, d = idx & 63;
    sh.ks[r][d] = lk_out[(size_t)r * STRIDE_HD + h * DD + d];
  }
  __syncthreads();
  if (tid < NF * 49) {                 // 98 4x4 tiles, single round
    int ff = tid / 49, rr2 = tid % 49;
    int it = rr2 / 7, kt = rr2 % 7;
    float acc[4][4] = {{0,0,0,0},{0,0,0,0},{0,0,0,0},{0,0,0,0}};
    #pragma unroll 4
    for (int d4 = 0; d4 < 16; ++d4) {
      f32x4 q0 = *(const f32x4*)&sh.qs[4 * it][4 * d4];
      f32x4 q1 = *(const f32x4*)&sh.qs[4 * it + 1][4 * d4];
      f32x4 q2 = *(const f32x4*)&sh.qs[4 * it + 2][4 * d4];
      f32x4 q3 = *(const f32x4*)&sh.qs[4 * it + 3][4 * d4];
      f32x4 k0 = *(const f32x4*)&sh.ks[ff * NB1 + 4 * kt][4 * d4];
      f32x4 k1 = *(const f32x4*)&sh.ks[ff * NB1 + 4 * kt + 1][4 * d4];
      f32x4 k2 = *(const f32x4*)&sh.ks[ff * NB1 + 4 * kt + 2][4 * d4];
      f32x4 k3 = *(const f32x4*)&sh.ks[ff * NB1 + 4 * kt + 3][4 * d4];
      #pragma unroll
      for (int dd = 0; dd < 4; ++dd) {
        float qv0 = q0[dd], qv1 = q1[dd], qv2 = q2[dd], qv3 = q3[dd];
        float kv0 = k0[dd], kv1 = k1[dd], kv2 = k2[dd], kv3 = k3[dd];
        acc[0][0] += qv0 * kv0; acc[0][1] += qv0 * kv1;
        acc[0][2] += qv0 * kv2; acc[0][3] += qv0 * kv3;
        acc[1][0] += qv1 * kv0; acc[1][1] += qv1 * kv1;
        acc[1][2] += qv1 * kv2; acc[1][3] += qv1 * kv3;
        acc[2][0] += qv2 * kv0; acc[2][1] += qv2 * kv1;
        acc[2][2] += qv2 * kv2; acc[2][3] += qv2 * kv3;
        acc[3][0] += qv3 * kv0; acc[3][1] += qv3 * kv1;
        acc[3][2] += qv3 * kv2; acc[3][3] += qv3 * kv3;
      }
    }
    size_t ob = (size_t)bid * (NF * NB1 * NB1) + (size_t)ff * (NB1 * NB1);
    #pragma unroll
    for (int r = 0; r < 4; ++r) {
      f32x4 res = {acc[r][0], acc[r][1], acc[r][2], acc[r][3]};
      *(f32x4*)&Lbuf[ob + (size_t)(4 * it + r) * NB1 + 4 * kt] = res;
    }
  }
}

__device__ void R_path(int bid, const float* __restrict__ rk,
                       const float* __restrict__ cosb, const float* __restrict__ sinb,
                       const float* __restrict__ rq_out, float* __restrict__ Rbuf,
                       MidRShared& sh) {
  const int h = bid / 112;             // 112 = 56 fk * 2 aa
  const int rem = bid % 112;
  const int fk = rem >> 1, aa = rem & 1;
  const int f = fk / NB1, k = fk % NB1;
  const int tid = threadIdx.x;
  for (int idx = tid; idx < NB2 * 32; idx += 256) {
    int l = idx >> 5, mm = idx & 31;
    int srow = f * (NB1 * NB2) + k * NB2 + l;
    const float* xr = rk + (size_t)srow * STRIDE_HD + h * DD;
    float x0 = xr[2 * mm], x1 = xr[2 * mm + 1];
    float co = cosb[srow * 32 + mm], si = sinb[srow * 32 + mm];
    sh.ks[l][2 * mm]     = x0 * co - x1 * si;
    sh.ks[l][2 * mm + 1] = x1 * co + x0 * si;
  }
  for (int idx = tid; idx < NB2 * DD; idx += 256) {
    int r2 = idx >> 6, d = idx & 63;
    sh.qs[r2][d] = rq_out[(size_t)(aa * NB2 + r2) * STRIDE_HD + h * DD + d];
  }
  __syncthreads();
  if (tid < 169) {                     // 13x13 4x4 tiles, single round
    int jt = tid / 13, lt = tid % 13;
    float acc[4][4] = {{0,0,0,0},{0,0,0,0},{0,0,0,0},{0,0,0,0}};
    #pragma unroll 4
    for (int d4 = 0; d4 < 16; ++d4) {
      f32x4 q0 = *(const f32x4*)&sh.qs[4 * jt][4 * d4];
      f32x4 q1 = *(const f32x4*)&sh.qs[4 * jt + 1][4 * d4];
      f32x4 q2 = *(const f32x4*)&sh.qs[4 * jt + 2][4 * d4];
      f32x4 q3 = *(const f32x4*)&sh.qs[4 * jt + 3][4 * d4];
      f32x4 k0 = *(const f32x4*)&sh.ks[4 * lt][4 * d4];
      f32x4 k1 = *(const f32x4*)&sh.ks[4 * lt + 1][4 * d4];
      f32x4 k2 = *(const f32x4*)&sh.ks[4 * lt + 2][4 * d4];
      f32x4 k3 = *(const f32x4*)&sh.ks[4 * lt + 3][4 * d4];
      #pragma unroll
      for (int dd = 0; dd < 4; ++dd) {
        float qv0 = q0[dd], qv1 = q1[dd], qv2 = q2[dd], qv3 = q3[dd];
        float kv0 = k0[dd], kv1 = k1[dd], kv2 = k2[dd], kv3 = k3[dd];
        acc[0][0] += qv0 * kv0; acc[0][1] += qv0 * kv1;
        acc[0][2] += qv0 * kv2; acc[0][3] += qv0 * kv3;
        acc[1][0] += qv1 * kv0; acc[1][1] += qv1 * kv1;
        acc[1][2] += qv1 * kv2; acc[1][3] += qv1 * kv3;
        acc[2][0] += qv2 * kv0; acc[2][1] += qv2 * kv1;
        acc[2][2] += qv2 * kv2; acc[2][3] += qv2 * kv3;
        acc[3][0] += qv3 * kv0; acc[3][1] += qv3 * kv1;
        acc[3][2] += qv3 * kv2; acc[3][3] += qv3 * kv3;
      }
    }
    #pragma unroll
    for (int r = 0; r < 4; ++r) {
      size_t rowb = ((size_t)(h * NF + aa) * NB2 + 4 * jt + r) * (size_t)(NF * NB1 * NB2)
                  + (size_t)fk * NB2 + 4 * lt;
      f32x4 res = {acc[r][0], acc[r][1], acc[r][2], acc[r][3]};
      *(f32x4*)&Rbuf[rowb] = res;
    }
  }
}

__global__ __launch_bounds__(256, 4)
void k_mid(const float* __restrict__ lq, const float* __restrict__ rk,
           const float* __restrict__ cosb, const float* __restrict__ sinb,
           const float* __restrict__ lk_out, const float* __restrict__ rq_out,
           float* __restrict__ Lbuf, float* __restrict__ Rbuf) {
  __shared__ __align__(16) MidShared sh;
  const int bx = blockIdx.x;
  if (bx < 1248) L_path(bx, lq, cosb, sinb, lk_out, Lbuf, sh.L);
  else           R_path(bx - 1248, rk, cosb, sinb, rq_out, Rbuf, sh.R);
}

// ===========================================================================
// MAIN: factorized flash attention. 4 waves = 4 fk-segments; each wave
// computes P once and does 2 MFMAs (both d-halves). No in-loop barriers.
// ===========================================================================
struct MainPro { float Ls2T[2][28][36]; float Rs[56][64]; };
union MainShared { MainPro p; float epil[4][16][64]; };

__global__ __launch_bounds__(256, 4)
void k_main(const float* __restrict__ Lbuf, const float* __restrict__ Rbuf,
            const unsigned short* __restrict__ vb2, float* __restrict__ outp) {
  const int bid0 = blockIdx.x;
  const int bid = (bid0 & 7) * 156 + (bid0 >> 3);   // 1248 = 8*156, XCD-chunked
  const int h = bid / (NF * NB2);
  const int rem = bid % (NF * NB2);
  const int a = rem / NB2, j = rem % NB2;
  const int tid = threadIdx.x;
  const int lane = tid & 63;
  const int w = tid >> 6;

  __shared__ __align__(16) MainShared ms;
  __shared__ float m2s[32], Rmx[FB1], Rmn[FB1], els[4][32];

  const float SC = SCALEF * 1.44269504f;
  for (int idx = tid; idx < NF * NB1 * NB1; idx += 256) {
    int ff = idx / 784, r2 = idx % 784;
    int i = r2 / 28, kk = r2 % 28;
    ms.p.Ls2T[ff][kk][i] = Lbuf[(size_t)bid * (NF * NB1 * NB1) + idx] * SC;
  }
  if (tid < 224) {                                    // zero pad rows i=28..31
    int ff = tid / 112, r2 = tid % 112;
    ms.p.Ls2T[ff][r2 >> 2][28 + (r2 & 3)] = 0.f;
  }
  for (int idx = tid; idx < FB1 * 13; idx += 256) {
    int fk = idx / 13, lc = idx % 13;
    float4 vv = ((const float4*)(Rbuf + (size_t)bid * (NF * NB1 * NB2)))[idx];
    *(float4*)&ms.p.Rs[fk][lc * 4] = vv;
  }
  if (tid >= 252) m2s[tid - 224] = 0.f;               // pad rows 28..31
  __syncthreads();

  if (tid < 224) {                                    // col max/min of R
    int fk = tid >> 2, part = tid & 3;
    float mx = -1e30f, mn = 1e30f;
    for (int l = part * 13; l < part * 13 + 13; ++l) {
      float x = ms.p.Rs[fk][l];
      mx = fmaxf(mx, x); mn = fminf(mn, x);
    }
    mx = fmaxf(mx, __shfl_xor(mx, 1)); mn = fminf(mn, __shfl_xor(mn, 1));
    mx = fmaxf(mx, __shfl_xor(mx, 2)); mn = fminf(mn, __shfl_xor(mn, 2));
    if (part == 0) { Rmx[fk] = mx; Rmn[fk] = mn; }
  }
  __syncthreads();

  if (tid < 224) {                                    // exact row max (log2 units)
    int i = tid >> 3, s = tid & 7;
    float m = -1e30f;
    #pragma unroll
    for (int n = 0; n < 7; ++n) {
      int fk = s + 8 * n;
      int ff = (fk >= NB1) ? 1 : 0, kk = fk - ff * NB1;
      float Lv = ms.p.Ls2T[ff][kk][i];
      m = fmaxf(m, fmaxf(Lv * Rmx[fk], Lv * Rmn[fk]));
    }
    m = fmaxf(m, __shfl_xor(m, 1));
    m = fmaxf(m, __shfl_xor(m, 2));
    m = fmaxf(m, __shfl_xor(m, 4));
    if (s == 0) m2s[i] = m;
  }
  __syncthreads();

  const int row = lane & 31;
  const int hi = lane >> 5;
  const float nm = -m2s[row];
  // vb2 layout: [h][fk][l8][d][li], bf16x8 granule index = fk*512 + l8*64 + d
  const bf16x8* vw = (const bf16x8*)vb2 + (size_t)h * 28672 + hi * 64 + row;

  f32x16 acc0 = {0.f,0.f,0.f,0.f,0.f,0.f,0.f,0.f,0.f,0.f,0.f,0.f,0.f,0.f,0.f,0.f};
  f32x16 acc1 = {0.f,0.f,0.f,0.f,0.f,0.f,0.f,0.f,0.f,0.f,0.f,0.f,0.f,0.f,0.f,0.f};
  float lsum = 0.f;

  for (int t = 0; t < 14; ++t) {
    const int fk = w * 14 + t;
    const float Lv = ms.p.Ls2T[w >> 1][(w & 1) * 14 + t][row];
    const bf16x8* vp = vw + (size_t)fk * 512;
    #pragma unroll
    for (int ks = 0; ks < 4; ++ks) {
      const int k0 = ks * 16 + hi * 8;
      float4 ra = *(const float4*)&ms.p.Rs[fk][k0];
      float4 rb = *(const float4*)&ms.p.Rs[fk][k0 + 4];
      float p0 = EXP2(fmaf(Lv, ra.x, nm));
      float p1 = EXP2(fmaf(Lv, ra.y, nm));
      float p2 = EXP2(fmaf(Lv, ra.z, nm));
      float p3 = EXP2(fmaf(Lv, ra.w, nm));
      float p4 = EXP2(fmaf(Lv, rb.x, nm));
      float p5 = EXP2(fmaf(Lv, rb.y, nm));
      float p6 = EXP2(fmaf(Lv, rb.z, nm));
      float p7 = EXP2(fmaf(Lv, rb.w, nm));
      if (ks == 3) {                                  // l = 48+hi*8+idx; mask l>=52
        if (hi == 0) { p4 = 0.f; p5 = 0.f; p6 = 0.f; p7 = 0.f; }
        else { p0 = 0.f; p1 = 0.f; p2 = 0.f; p3 = 0.f;
               p4 = 0.f; p5 = 0.f; p6 = 0.f; p7 = 0.f; }
      }
      lsum += ((p0 + p1) + (p2 + p3)) + ((p4 + p5) + (p6 + p7));
      union { bf16x8 v8; __hip_bfloat162 h2[4]; } pk;
      pk.h2[0] = __float22bfloat162_rn(make_float2(p0, p1));
      pk.h2[1] = __float22bfloat162_rn(make_float2(p2, p3));
      pk.h2[2] = __float22bfloat162_rn(make_float2(p4, p5));
      pk.h2[3] = __float22bfloat162_rn(make_float2(p6, p7));
      bf16x8 b0 = vp[ks * 128];
      bf16x8 b1 = vp[ks * 128 + 32];
      acc0 = __builtin_amdgcn_mfma_f32_32x32x16_bf16(pk.v8, b0, acc0, 0, 0, 0);
      acc1 = __builtin_amdgcn_mfma_f32_32x32x16_bf16(pk.v8, b1, acc1, 0, 0, 0);
    }
  }

  lsum += __shfl_xor(lsum, 32);
  if (lane < 32) els[w][lane] = lsum;
  __syncthreads();                                     // Rs/Ls2T reads done; els visible

  // epilogue: 2 rounds (d-halves) of 4-segment reduction through LDS
  #pragma unroll
  for (int half = 0; half < 2; ++half) {
    if (half) __syncthreads();
    #pragma unroll
    for (int r = 0; r < 16; ++r)
      ms.epil[w][r][lane] = half ? acc1[r] : acc0[r];
    __syncthreads();
    #pragma unroll
    for (int q = 0; q < 4; ++q) {
      int r = (tid >> 6) + q * 4;
      int elane = tid & 63;
      float val = ms.epil[0][r][elane] + ms.epil[1][r][elane]
                + ms.epil[2][r][elane] + ms.epil[3][r][elane];
      int irow = (r & 3) + 8 * (r >> 2) + 4 * (elane >> 5);
      if (irow < NB1) {
        float li = 1.0f / (els[0][irow] + els[1][irow] + els[2][irow] + els[3][irow]);
        int srow = a * (NB1 * NB2) + irow * NB2 + j;
        int d = half * 32 + (elane & 31);
        outp[(size_t)srow * STRIDE_HD + h * DD + d] = val * li;
      }
    }
  }
}

// ---------------------------------------------------------------------------
extern "C" void kernel_launch(void* const* d_in, const int* in_sizes, int n_in,
                              void* d_out, int out_size, void* d_ws, size_t ws_size,
                              hipStream_t stream) {
  (void)in_sizes; (void)n_in; (void)out_size; (void)ws_size;
  const float* lq   = (const float*)d_in[0];
  const float* lk   = (const float*)d_in[1];
  const float* rq   = (const float*)d_in[2];
  const float* rk   = (const float*)d_in[3];
  const float* v    = (const float*)d_in[4];
  const float* cosb = (const float*)d_in[5];
  const float* sinb = (const float*)d_in[6];
  const float* W_lkq = (const float*)d_in[7];  const float* b_lkq = (const float*)d_in[8];
  const float* W_lkk = (const float*)d_in[9];  const float* b_lkk = (const float*)d_in[10];
  const float* W_lkv = (const float*)d_in[11]; const float* b_lkv = (const float*)d_in[12];
  const float* W_rqq = (const float*)d_in[13]; const float* b_rqq = (const float*)d_in[14];
  const float* W_rqk = (const float*)d_in[15]; const float* b_rqk = (const float*)d_in[16];
  const float* W_rqv = (const float*)d_in[17]; const float* b_rqv = (const float*)d_in[18];

  float* ws = (float*)d_ws;
  float* lk_out = ws;                                   // 43008
  float* rq_out = ws + 43008;                           // 79872
  float* Lbuf   = ws + 122880;                          // 1956864
  float* Rbuf   = ws + 2079744;                         // 3634176
  unsigned short* vb2 = (unsigned short*)(ws + 5713920);// 2752512 shorts
  float* ql     = ws + 7090176;                         // 43008
  float* qr     = ws + 7133184;                         // 79872
  // Klg/Krg alias the Lbuf/Rbuf space (dead before k_mid writes them)
  float* Klg = Lbuf;                                    // 2236416
  float* Krg = Lbuf + 2236416;                          // 2236416 (ends < Rbuf end)

  k_proj<<<1140, 256, 0, stream>>>(lk, rq, cosb, sinb,
      W_lkk, b_lkk, W_rqk, b_rqk, W_lkq, b_lkq, W_rqq, b_rqq,
      Klg, Krg, ql, qr);
  k_sv<<<2592, 256, 0, stream>>>(lk, rq, v, cosb, sinb, Klg, Krg, ql, qr,
      W_lkv, b_lkv, W_rqv, b_rqv, lk_out, rq_out, vb2);
  k_mid<<<2592, 256, 0, stream>>>(lq, rk, cosb, sinb, lk_out, rq_out, Lbuf, Rbuf);
  k_main<<<1248, 256, 0, stream>>>(Lbuf, Rbuf, vb2, (float*)d_out);
}